// Round 22
// baseline (659.073 us; speedup 1.0000x reference)
//
#include <hip/hip_runtime.h>

#define NB 32
#define LL 2048
#define DD 1024      // D2
#define AA 512       // ATTN
#define TT 8
#define LOG2E 1.4426950408889634f

typedef short short8 __attribute__((ext_vector_type(8)));
typedef float f32x4 __attribute__((ext_vector_type(4)));

#if __has_builtin(__builtin_amdgcn_exp2f)
#define EXP2(x) __builtin_amdgcn_exp2f(x)
#else
#define EXP2(x) exp2f(x)
#endif
#if __has_builtin(__builtin_amdgcn_rcpf)
#define RCP(x) __builtin_amdgcn_rcpf(x)
#else
#define RCP(x) (1.0f/(x))
#endif

__device__ __forceinline__ unsigned short f2b(float f){
  union { float f; unsigned u; } v; v.f = f;
  unsigned r = v.u + 0x7fffu + ((v.u >> 16) & 1u);
  return (unsigned short)(r >> 16);
}
__device__ __forceinline__ float b2f(unsigned short b){
  union { unsigned u; float f; } v; v.u = ((unsigned)b) << 16;
  return v.f;
}
__device__ __forceinline__ float sigm(float x){
  return RCP(1.f + EXP2(-x * LOG2E));
}
__device__ __forceinline__ float tanh_f(float x){
  return 2.f * RCP(1.f + EXP2(-2.f * LOG2E * x)) - 1.f;
}
__device__ __forceinline__ void gll16(const void* g, void* l){
  __builtin_amdgcn_global_load_lds(
      (const __attribute__((address_space(1))) unsigned int*)(g),
      (__attribute__((address_space(3))) unsigned int*)(l),
      16, 0, 0);
}

// ---- fp8 e4m3 (OCP) encode/decode, HW builtin with SW fallback ----
__device__ __forceinline__ unsigned char sw_enc_e4m3(float f){
  union{float f;unsigned u;} v; v.f = f;
  unsigned s = (v.u>>31)<<7;
  float a = fabsf(f);
  if (a < 0.015625f){
    int q = (int)(a*512.f + 0.5f);
    if (q > 7) return s | (1<<3);
    return s | q;
  }
  int e = ((v.u>>23)&255) - 127;
  unsigned m = ((v.u & 0x7FFFFF) + 0x80000) >> 20;
  if (m == 8){ m = 0; e++; }
  int eb = e + 7;
  if (eb > 15){ eb = 15; m = 6; }
  if (eb <= 0){
    int q = (int)(a*512.f + 0.5f); if (q>7) q=7;
    return s | q;
  }
  return s | (eb<<3) | m;
}
__device__ __forceinline__ unsigned char f2e8(float f){
#if __has_builtin(__builtin_amdgcn_cvt_pk_fp8_f32)
  return (unsigned char)(__builtin_amdgcn_cvt_pk_fp8_f32(f, f, 0, false) & 0xFF);
#else
  return sw_enc_e4m3(f);
#endif
}
__device__ __forceinline__ float sw_dec_e4m3(unsigned char c){
  unsigned s = c>>7, e = (c>>3)&15, m = c&7;
  if (e){ union{unsigned u;float f;} x; x.u = (s<<31)|((e+120)<<23)|(m<<20); return x.f; }
  float r = (float)m * 0.001953125f;
  return s ? -r : r;
}
#if __has_builtin(__builtin_amdgcn_cvt_f32_fp8)
#define DEC8(word, sel) __builtin_amdgcn_cvt_f32_fp8((int)(word), (sel))
#else
#define DEC8(word, sel) sw_dec_e4m3((unsigned char)(((word) >> ((sel)*8)) & 0xFF))
#endif
#define DEC8X4(dst, word) do { \
    (dst)[0] = DEC8((word), 0); (dst)[1] = DEC8((word), 1); \
    (dst)[2] = DEC8((word), 2); (dst)[3] = DEC8((word), 3); } while(0)

// ---- unified cvt: enc->fp8, Wih/Whh->fp8 x32, W1->bf16, W2->fp8 x32 ------
__global__ __launch_bounds__(256) void k_cvt_all(
    const float* __restrict__ enc, const float* __restrict__ wih,
    const float* __restrict__ whh, const float* __restrict__ w1,
    const float* __restrict__ w2,
    unsigned char* __restrict__ enc8, unsigned char* __restrict__ wih8,
    unsigned char* __restrict__ whh8, unsigned short* __restrict__ w1b,
    unsigned char* __restrict__ w28,
    long ce, long cw, long c1, long c2)   // counts in 8-elem units
{
  const long total = ce + 2*cw + c1 + c2;
  const long stride = (long)gridDim.x * 256;
  for (long i = (long)blockIdx.x*256 + threadIdx.x; i < total; i += stride){
    long idx = i;
    const float* s; float sc; unsigned char* d8 = 0; unsigned short* db = 0;
    if (idx < ce){ s = enc; sc = 1.f; d8 = enc8; }
    else { idx -= ce;
      if (idx < cw){ s = wih; sc = 32.f; d8 = wih8; }
      else { idx -= cw;
        if (idx < cw){ s = whh; sc = 32.f; d8 = whh8; }
        else { idx -= cw;
          if (idx < c1){ s = w1; sc = 1.f; db = w1b; }
          else { idx -= c1; s = w2; sc = 32.f; d8 = w28; } } } }
    const float4* ip = (const float4*)(s + idx*8);
    float4 a = ip[0], b = ip[1];
    if (db){
      uint4 o;
      o.x = (unsigned)f2b(a.x) | ((unsigned)f2b(a.y) << 16);
      o.y = (unsigned)f2b(a.z) | ((unsigned)f2b(a.w) << 16);
      o.z = (unsigned)f2b(b.x) | ((unsigned)f2b(b.y) << 16);
      o.w = (unsigned)f2b(b.z) | ((unsigned)f2b(b.w) << 16);
      *(uint4*)(db + idx*8) = o;
    } else {
      uint2 p;
      p.x = (unsigned)f2e8(a.x*sc) | ((unsigned)f2e8(a.y*sc)<<8) |
            ((unsigned)f2e8(a.z*sc)<<16) | ((unsigned)f2e8(a.w*sc)<<24);
      p.y = (unsigned)f2e8(b.x*sc) | ((unsigned)f2e8(b.y*sc)<<8) |
            ((unsigned)f2e8(b.z*sc)<<16) | ((unsigned)f2e8(b.w*sc)<<24);
      *(uint2*)(d8 + idx*8) = p;
    }
  }
}

// ---------------- enc_proj GEMM, fp8 x fp8, 128x128 tile, XOR swizzle ------
__global__ __launch_bounds__(256) void k_gemm8(
    const unsigned char* __restrict__ A,   // [65536,1024] fp8 enc
    const unsigned char* __restrict__ Bt,  // [512,1024] fp8 (W2*32)
    const float* __restrict__ b2,
    unsigned char* __restrict__ C8)        // [65536,512] fp8 ep
{
  __shared__ unsigned char As[128*64];
  __shared__ unsigned char Bs[128*64];
  const int tid = threadIdx.x;
  const int wid = tid >> 6, lane = tid & 63;
  const int wm = wid >> 1, wn = wid & 1;
  const int hi = lane >> 4, r = lane & 15;
  const long brow = (long)blockIdx.x * 128;
  const int bcol = blockIdx.y * 128;
  const int srow = wid*32 + (lane >> 2);
  const int scol = (((lane & 3) ^ ((lane >> 3) & 3)) << 4);
  const unsigned char* aS0 = A + (brow + srow)*1024 + scol;
  const unsigned char* aS1 = A + (brow + srow + 16)*1024 + scol;
  const unsigned char* bS0 = Bt + (long)(bcol + srow)*1024 + scol;
  const unsigned char* bS1 = Bt + (long)(bcol + srow + 16)*1024 + scol;
  char* aD = (char*)As + wid*2048;
  char* bD = (char*)Bs + wid*2048;

  f32x4 acc[4][4];
  #pragma unroll
  for (int i=0;i<4;i++)
    #pragma unroll
    for (int j=0;j<4;j++) acc[i][j] = (f32x4){0.f,0.f,0.f,0.f};

  const int sw = (r >> 1) & 3;
  const int c0 = hi >> 1;
  const int h8 = (hi & 1) * 8;
  const int p0 = ((c0 ^ sw) << 4) + h8;

  for (int k0 = 0; k0 < 1024; k0 += 64){
    __syncthreads();
    gll16(aS0 + k0, aD);
    gll16(aS1 + k0, aD + 1024);
    gll16(bS0 + k0, bD);
    gll16(bS1 + k0, bD + 1024);
    __syncthreads();
    long af[4][2], bfr[4][2];
    #pragma unroll
    for (int fm=0; fm<4; fm++){
      const char* base = (const char*)As + (wm*64 + fm*16 + r)*64;
      af[fm][0] = *(const long*)(base + p0);
      af[fm][1] = *(const long*)(base + (p0 ^ 32));
    }
    #pragma unroll
    for (int fn=0; fn<4; fn++){
      const char* base = (const char*)Bs + (wn*64 + fn*16 + r)*64;
      bfr[fn][0] = *(const long*)(base + p0);
      bfr[fn][1] = *(const long*)(base + (p0 ^ 32));
    }
    #pragma unroll
    for (int fm=0; fm<4; fm++)
      #pragma unroll
      for (int fn=0; fn<4; fn++){
        acc[fm][fn] = __builtin_amdgcn_mfma_f32_16x16x32_fp8_fp8(af[fm][0], bfr[fn][0], acc[fm][fn], 0, 0, 0);
        acc[fm][fn] = __builtin_amdgcn_mfma_f32_16x16x32_fp8_fp8(af[fm][1], bfr[fn][1], acc[fm][fn], 0, 0, 0);
      }
  }
  const float inv32 = 1.f/32.f;
  #pragma unroll
  for (int fm=0; fm<4; fm++){
    #pragma unroll
    for (int fn=0; fn<4; fn++){
      int col = bcol + wn*64 + fn*16 + r;
      float bias = b2[col];
      #pragma unroll
      for (int q=0; q<4; q++){
        long row = brow + wm*64 + fm*16 + hi*4 + q;
        C8[row*512 + col] = f2e8(acc[fm][fn][q]*inv32 + bias);
      }
    }
  }
}

// ---- fused LSTM: gates (4 rows per wave, same d) + cell; fp8 weights -----
__global__ __launch_bounds__(256) void k_glstm(
    const float* __restrict__ x, const float* __restrict__ h_in,
    const float* __restrict__ c_in,
    const unsigned char* __restrict__ Wih, const unsigned char* __restrict__ Whh,
    const float* __restrict__ b_ih, const float* __restrict__ b_hh,
    float* __restrict__ h_out, float* __restrict__ c_out, int first)
{
  const int wid = threadIdx.x >> 6, lane = threadIdx.x & 63;
  const int d = (blockIdx.x >> 1)*4 + wid;
  const int n0 = (blockIdx.x & 1) << 4;
  float wi[4][16], wh[4][16], bias[4];
  #pragma unroll
  for (int g=0; g<4; g++){
    const int rg = g*1024 + d;
    const long wo = (long)rg*1024 + lane*16;
    uint4 vi = *(const uint4*)(Wih + wo);
    uint4 vh = *(const uint4*)(Whh + wo);
    DEC8X4(&wi[g][0],  vi.x); DEC8X4(&wi[g][4],  vi.y);
    DEC8X4(&wi[g][8],  vi.z); DEC8X4(&wi[g][12], vi.w);
    DEC8X4(&wh[g][0],  vh.x); DEC8X4(&wh[g][4],  vh.y);
    DEC8X4(&wh[g][8],  vh.z); DEC8X4(&wh[g][12], vh.w);
    bias[g] = b_ih[rg] + b_hh[rg];
  }
  const float inv32 = 1.f/32.f;
  for (int n=n0; n<n0+16; n++){
    const float4* hp = (const float4*)(h_in + n*1024 + lane*16);
    float ha[16];
    *(float4*)(ha+0)=hp[0]; *(float4*)(ha+4)=hp[1]; *(float4*)(ha+8)=hp[2]; *(float4*)(ha+12)=hp[3];
    float s0=0.f, s1=0.f, s2=0.f, s3=0.f;
    if (first){
      #pragma unroll
      for (int i=0;i<16;i++){
        s0 += ha[i]*wh[0][i]; s1 += ha[i]*wh[1][i];
        s2 += ha[i]*wh[2][i]; s3 += ha[i]*wh[3][i];
      }
    } else {
      const float4* xp = (const float4*)(x + n*1024 + lane*16);
      float xa[16];
      *(float4*)(xa+0)=xp[0]; *(float4*)(xa+4)=xp[1]; *(float4*)(xa+8)=xp[2]; *(float4*)(xa+12)=xp[3];
      #pragma unroll
      for (int i=0;i<16;i++){
        s0 += xa[i]*wi[0][i] + ha[i]*wh[0][i];
        s1 += xa[i]*wi[1][i] + ha[i]*wh[1][i];
        s2 += xa[i]*wi[2][i] + ha[i]*wh[2][i];
        s3 += xa[i]*wi[3][i] + ha[i]*wh[3][i];
      }
    }
    #pragma unroll
    for (int o=32;o>0;o>>=1){
      s0 += __shfl_xor(s0, o); s1 += __shfl_xor(s1, o);
      s2 += __shfl_xor(s2, o); s3 += __shfl_xor(s3, o);
    }
    if (lane == 0){
      const int idx = n*1024 + d;
      float gi = sigm(s0*inv32 + bias[0]);
      float gf = sigm(s1*inv32 + bias[1]);
      float gg = tanh_f(s2*inv32 + bias[2]);
      float go = sigm(s3*inv32 + bias[3]);
      float cn = gf*c_in[idx] + gi*gg;
      c_out[idx] = cn;
      h_out[idx] = go * tanh_f(cn);
    }
  }
}

// ---------------- q projection: wave-per-2j, n split over 2 blocks --------
__global__ __launch_bounds__(256) void k_q(
    const float* __restrict__ h, const unsigned short* __restrict__ W1,
    const float* __restrict__ b1, float* __restrict__ q)
{
  const int wid = threadIdx.x >> 6, lane = threadIdx.x & 63;
  const int jgrp = blockIdx.x >> 1;
  const int n0 = (blockIdx.x & 1) << 4;
  const int j0 = (jgrp*4 + wid)*2;
  float wf[2][16], bias[2];
  #pragma unroll
  for (int jj=0;jj<2;jj++){
    const long wo = (long)(j0+jj)*1024 + lane*16;
    short8 w0 = *(const short8*)(W1 + wo);
    short8 w1 = *(const short8*)(W1 + wo + 8);
    #pragma unroll
    for (int i=0;i<8;i++){ wf[jj][i] = b2f((unsigned short)w0[i]); wf[jj][i+8] = b2f((unsigned short)w1[i]); }
    bias[jj] = b1[j0+jj];
  }
  for (int n=n0; n<n0+16; n++){
    const float4* hp = (const float4*)(h + n*1024 + lane*16);
    float ha[16];
    *(float4*)(ha+0)=hp[0]; *(float4*)(ha+4)=hp[1]; *(float4*)(ha+8)=hp[2]; *(float4*)(ha+12)=hp[3];
    float s0=0.f, s1=0.f;
    #pragma unroll
    for (int i=0;i<16;i++){ s0 += ha[i]*wf[0][i]; s1 += ha[i]*wf[1][i]; }
    #pragma unroll
    for (int o=32;o>0;o>>=1){ s0 += __shfl_xor(s0, o); s1 += __shfl_xor(s1, o); }
    if (lane == 0){ q[n*AA + j0] = s0 + bias[0]; q[n*AA + j0 + 1] = s1 + bias[1]; }
  }
}

// ---- fused attn + softmax(no-max) + x_next partials (fp8, XCD-remap) -----
__global__ __launch_bounds__(256) void k_attnx(
    const unsigned char* __restrict__ ep8, const float* __restrict__ qv,
    const float* __restrict__ w3, const float* __restrict__ b3p,
    const int* __restrict__ mask, const unsigned char* __restrict__ enc8,
    float* __restrict__ out, float* __restrict__ part,
    float* __restrict__ psum, int t)
{
  // XCD-aware remap (bijective over 1024 blocks): each XCD owns 4 n-slices
  const int linear = blockIdx.y * 32 + blockIdx.x;
  const int xcd = linear & 7;
  const int qq  = linear >> 3;          // 0..127
  const int ch  = qq & 31;
  const int n   = xcd * 4 + (qq >> 5);  // 0..31
  const int tid = threadIdx.x;
  const int wid = tid >> 6, lane = tid & 63;
  __shared__ float p_s[64];

  float qf[8], w3f[8];
  const float4* qp = (const float4*)(qv + n*AA + lane*8);
  *(float4*)(qf+0) = qp[0]; *(float4*)(qf+4) = qp[1];
  const float4* wp = (const float4*)(w3 + lane*8);
  *(float4*)(w3f+0) = wp[0]; *(float4*)(w3f+4) = wp[1];
  const float b3v = b3p[0];

  #pragma unroll 1
  for (int li = 0; li < 16; li++){
    const int l = ch*64 + wid*16 + li;
    uint2 e = *(const uint2*)(ep8 + ((long)n*LL + l)*AA + lane*8);
    float ef[8];
    DEC8X4(&ef[0], e.x); DEC8X4(&ef[4], e.y);
    float s = 0.f;
    #pragma unroll
    for (int i=0;i<8;i++) s += tanh_f(ef[i] + qf[i]) * w3f[i];
    #pragma unroll
    for (int o=32;o>0;o>>=1) s += __shfl_xor(s, o);
    if (lane == 0){
      float a = s + b3v;
      int mk = mask[n*LL + l];
      float aout = a;
      if (!mk) aout += -1e30f;
      out[((long)n*TT + t)*LL + l] = aout;
      p_s[wid*16 + li] = mk ? EXP2(a*LOG2E) : 0.f;
    }
  }
  __syncthreads();

  const unsigned char* base = enc8 + ((long)n*LL + ch*64)*1024 + tid*4;
  float a0=0.f, a1=0.f, a2=0.f, a3=0.f;
  #pragma unroll 4
  for (int li=0; li<64; li++){
    float pv = p_s[li];
    unsigned u = *(const unsigned*)(base + (long)li*1024);
    a0 = fmaf(pv, DEC8(u,0), a0);
    a1 = fmaf(pv, DEC8(u,1), a1);
    a2 = fmaf(pv, DEC8(u,2), a2);
    a3 = fmaf(pv, DEC8(u,3), a3);
  }
  float4 o = {a0,a1,a2,a3};
  *(float4*)(part + ((long)(n*32+ch))*1024 + tid*4) = o;
  if (tid == 0){
    float S = 0.f;
    #pragma unroll
    for (int i=0;i<64;i++) S += p_s[i];
    psum[n*32 + ch] = S;
  }
}

// ---------------- reduce partials -> x (divide by total sum) --------------
__global__ __launch_bounds__(256) void k_xreduce(const float* __restrict__ part,
                                                 const float* __restrict__ psum,
                                                 float* __restrict__ x){
  int idx = blockIdx.x*256 + threadIdx.x;
  int n = idx >> 10, d = idx & 1023;
  float S = 0.f;
  #pragma unroll
  for (int ch=0; ch<32; ch++) S += psum[n*32 + ch];
  float s = 0.f;
  #pragma unroll
  for (int ch=0; ch<32; ch++) s += part[((long)(n*32+ch))*1024 + d];
  x[idx] = s * RCP(S);
}

extern "C" void kernel_launch(void* const* d_in, const int* in_sizes, int n_in,
                              void* d_out, int out_size, void* d_ws, size_t ws_size,
                              hipStream_t stream){
  const float* enc_f = (const float*)d_in[0];
  const float* h0    = (const float*)d_in[1];
  const float* c0    = (const float*)d_in[2];
  const int*   mask  = (const int*)d_in[3];
  const float* Wih_f = (const float*)d_in[4];
  const float* Whh_f = (const float*)d_in[5];
  const float* b_ih  = (const float*)d_in[6];
  const float* b_hh  = (const float*)d_in[7];
  const float* W1_f  = (const float*)d_in[8];
  const float* b1    = (const float*)d_in[9];
  const float* W2_f  = (const float*)d_in[10];
  const float* b2    = (const float*)d_in[11];
  const float* w3    = (const float*)d_in[12];
  const float* b3    = (const float*)d_in[13];
  float* out = (float*)d_out;

  char* ws = (char*)d_ws;
  size_t off = 0;
  auto alloc = [&](size_t bytes){ void* p = ws + off; off += (bytes + 255) & ~255ull; return p; };
  unsigned char*  enc_8 = (unsigned char*)alloc((size_t)NB*LL*DD);     // 64 MB fp8
  unsigned char*  ep_8  = (unsigned char*)alloc((size_t)NB*LL*AA);     // 32 MB fp8
  unsigned char*  Wih_8 = (unsigned char*)alloc((size_t)4*DD*DD);      // 4 MB fp8 x32
  unsigned char*  Whh_8 = (unsigned char*)alloc((size_t)4*DD*DD);      // 4 MB fp8 x32
  unsigned short* W1_b  = (unsigned short*)alloc((size_t)AA*DD*2);
  unsigned char*  W2_8  = (unsigned char*)alloc((size_t)AA*DD);        // fp8 x32
  float* hA    = (float*)alloc((size_t)NB*DD*4);
  float* hB    = (float*)alloc((size_t)NB*DD*4);
  float* cbuf  = (float*)alloc((size_t)NB*DD*4);
  float* xbuf  = (float*)alloc((size_t)NB*DD*4);
  float* qbuf  = (float*)alloc((size_t)NB*AA*4);
  float* part  = (float*)alloc((size_t)NB*32*DD*4);
  float* psum  = (float*)alloc((size_t)NB*32*4);

  k_cvt_all<<<4096,256,0,stream>>>(enc_f, Wih_f, Whh_f, W1_f, W2_f,
                                   enc_8, Wih_8, Whh_8, W1_b, W2_8,
                                   (long)NB*LL*DD/8, (long)4*DD*DD/8,
                                   (long)AA*DD/8, (long)AA*DD/8);
  k_gemm8<<<dim3(512,4),256,0,stream>>>(enc_8, W2_8, b2, ep_8);

  float* hcur = hA; float* hnxt = hB;
  for (int t=0; t<TT; t++){
    k_glstm<<<512,256,0,stream>>>(xbuf,
                                  t==0 ? h0 : hcur,
                                  t==0 ? c0 : cbuf,
                                  Wih_8, Whh_8, b_ih, b_hh,
                                  hnxt, cbuf, t==0 ? 1 : 0);
    k_q<<<128,256,0,stream>>>(hnxt, W1_b, b1, qbuf);
    k_attnx<<<dim3(32,NB),256,0,stream>>>(ep_8, qbuf, w3, b3, mask, enc_8,
                                          out, part, psum, t);
    k_xreduce<<<128,256,0,stream>>>(part, psum, xbuf);
    float* tmp = hcur; hcur = hnxt; hnxt = tmp;
  }
}

// Round 23
// 627.173 us; speedup vs baseline: 1.0509x; 1.0509x over previous
//
#include <hip/hip_runtime.h>

#define NB 32
#define LL 2048
#define DD 1024      // D2
#define AA 512       // ATTN
#define TT 8
#define LOG2E 1.4426950408889634f

typedef short short8 __attribute__((ext_vector_type(8)));
typedef float f32x4 __attribute__((ext_vector_type(4)));

#if __has_builtin(__builtin_amdgcn_exp2f)
#define EXP2(x) __builtin_amdgcn_exp2f(x)
#else
#define EXP2(x) exp2f(x)
#endif
#if __has_builtin(__builtin_amdgcn_rcpf)
#define RCP(x) __builtin_amdgcn_rcpf(x)
#else
#define RCP(x) (1.0f/(x))
#endif

__device__ __forceinline__ unsigned short f2b(float f){
  union { float f; unsigned u; } v; v.f = f;
  unsigned r = v.u + 0x7fffu + ((v.u >> 16) & 1u);
  return (unsigned short)(r >> 16);
}
__device__ __forceinline__ float b2f(unsigned short b){
  union { unsigned u; float f; } v; v.u = ((unsigned)b) << 16;
  return v.f;
}
__device__ __forceinline__ float sigm(float x){
  return RCP(1.f + EXP2(-x * LOG2E));
}
__device__ __forceinline__ float tanh_f(float x){
  return 2.f * RCP(1.f + EXP2(-2.f * LOG2E * x)) - 1.f;
}
__device__ __forceinline__ void gll16(const void* g, void* l){
  __builtin_amdgcn_global_load_lds(
      (const __attribute__((address_space(1))) unsigned int*)(g),
      (__attribute__((address_space(3))) unsigned int*)(l),
      16, 0, 0);
}

// ---- fp8 e4m3 (OCP) encode/decode, HW builtin with SW fallback ----
__device__ __forceinline__ unsigned char sw_enc_e4m3(float f){
  union{float f;unsigned u;} v; v.f = f;
  unsigned s = (v.u>>31)<<7;
  float a = fabsf(f);
  if (a < 0.015625f){
    int q = (int)(a*512.f + 0.5f);
    if (q > 7) return s | (1<<3);
    return s | q;
  }
  int e = ((v.u>>23)&255) - 127;
  unsigned m = ((v.u & 0x7FFFFF) + 0x80000) >> 20;
  if (m == 8){ m = 0; e++; }
  int eb = e + 7;
  if (eb > 15){ eb = 15; m = 6; }
  if (eb <= 0){
    int q = (int)(a*512.f + 0.5f); if (q>7) q=7;
    return s | q;
  }
  return s | (eb<<3) | m;
}
__device__ __forceinline__ unsigned char f2e8(float f){
#if __has_builtin(__builtin_amdgcn_cvt_pk_fp8_f32)
  return (unsigned char)(__builtin_amdgcn_cvt_pk_fp8_f32(f, f, 0, false) & 0xFF);
#else
  return sw_enc_e4m3(f);
#endif
}
__device__ __forceinline__ float sw_dec_e4m3(unsigned char c){
  unsigned s = c>>7, e = (c>>3)&15, m = c&7;
  if (e){ union{unsigned u;float f;} x; x.u = (s<<31)|((e+120)<<23)|(m<<20); return x.f; }
  float r = (float)m * 0.001953125f;
  return s ? -r : r;
}
#if __has_builtin(__builtin_amdgcn_cvt_f32_fp8)
#define DEC8(word, sel) __builtin_amdgcn_cvt_f32_fp8((int)(word), (sel))
#else
#define DEC8(word, sel) sw_dec_e4m3((unsigned char)(((word) >> ((sel)*8)) & 0xFF))
#endif
#define DEC8X4(dst, word) do { \
    (dst)[0] = DEC8((word), 0); (dst)[1] = DEC8((word), 1); \
    (dst)[2] = DEC8((word), 2); (dst)[3] = DEC8((word), 3); } while(0)

// ---- unified cvt: enc->fp8, Wih/Whh->fp8 x32, W1->bf16, W2->fp8 x32 ------
__global__ __launch_bounds__(256) void k_cvt_all(
    const float* __restrict__ enc, const float* __restrict__ wih,
    const float* __restrict__ whh, const float* __restrict__ w1,
    const float* __restrict__ w2,
    unsigned char* __restrict__ enc8, unsigned char* __restrict__ wih8,
    unsigned char* __restrict__ whh8, unsigned short* __restrict__ w1b,
    unsigned char* __restrict__ w28,
    long ce, long cw, long c1, long c2)   // counts in 8-elem units
{
  const long total = ce + 2*cw + c1 + c2;
  const long stride = (long)gridDim.x * 256;
  for (long i = (long)blockIdx.x*256 + threadIdx.x; i < total; i += stride){
    long idx = i;
    const float* s; float sc; unsigned char* d8 = 0; unsigned short* db = 0;
    if (idx < ce){ s = enc; sc = 1.f; d8 = enc8; }
    else { idx -= ce;
      if (idx < cw){ s = wih; sc = 32.f; d8 = wih8; }
      else { idx -= cw;
        if (idx < cw){ s = whh; sc = 32.f; d8 = whh8; }
        else { idx -= cw;
          if (idx < c1){ s = w1; sc = 1.f; db = w1b; }
          else { idx -= c1; s = w2; sc = 32.f; d8 = w28; } } } }
    const float4* ip = (const float4*)(s + idx*8);
    float4 a = ip[0], b = ip[1];
    if (db){
      uint4 o;
      o.x = (unsigned)f2b(a.x) | ((unsigned)f2b(a.y) << 16);
      o.y = (unsigned)f2b(a.z) | ((unsigned)f2b(a.w) << 16);
      o.z = (unsigned)f2b(b.x) | ((unsigned)f2b(b.y) << 16);
      o.w = (unsigned)f2b(b.z) | ((unsigned)f2b(b.w) << 16);
      *(uint4*)(db + idx*8) = o;
    } else {
      uint2 p;
      p.x = (unsigned)f2e8(a.x*sc) | ((unsigned)f2e8(a.y*sc)<<8) |
            ((unsigned)f2e8(a.z*sc)<<16) | ((unsigned)f2e8(a.w*sc)<<24);
      p.y = (unsigned)f2e8(b.x*sc) | ((unsigned)f2e8(b.y*sc)<<8) |
            ((unsigned)f2e8(b.z*sc)<<16) | ((unsigned)f2e8(b.w*sc)<<24);
      *(uint2*)(d8 + idx*8) = p;
    }
  }
}

// ---------------- enc_proj GEMM, fp8 x fp8, 128x128 tile, XOR swizzle ------
__global__ __launch_bounds__(256) void k_gemm8(
    const unsigned char* __restrict__ A,   // [65536,1024] fp8 enc
    const unsigned char* __restrict__ Bt,  // [512,1024] fp8 (W2*32)
    const float* __restrict__ b2,
    unsigned char* __restrict__ C8)        // [65536,512] fp8 ep
{
  __shared__ unsigned char As[128*64];
  __shared__ unsigned char Bs[128*64];
  const int tid = threadIdx.x;
  const int wid = tid >> 6, lane = tid & 63;
  const int wm = wid >> 1, wn = wid & 1;
  const int hi = lane >> 4, r = lane & 15;
  const long brow = (long)blockIdx.x * 128;
  const int bcol = blockIdx.y * 128;
  const int srow = wid*32 + (lane >> 2);
  const int scol = (((lane & 3) ^ ((lane >> 3) & 3)) << 4);
  const unsigned char* aS0 = A + (brow + srow)*1024 + scol;
  const unsigned char* aS1 = A + (brow + srow + 16)*1024 + scol;
  const unsigned char* bS0 = Bt + (long)(bcol + srow)*1024 + scol;
  const unsigned char* bS1 = Bt + (long)(bcol + srow + 16)*1024 + scol;
  char* aD = (char*)As + wid*2048;
  char* bD = (char*)Bs + wid*2048;

  f32x4 acc[4][4];
  #pragma unroll
  for (int i=0;i<4;i++)
    #pragma unroll
    for (int j=0;j<4;j++) acc[i][j] = (f32x4){0.f,0.f,0.f,0.f};

  const int sw = (r >> 1) & 3;
  const int c0 = hi >> 1;
  const int h8 = (hi & 1) * 8;
  const int p0 = ((c0 ^ sw) << 4) + h8;

  for (int k0 = 0; k0 < 1024; k0 += 64){
    __syncthreads();
    gll16(aS0 + k0, aD);
    gll16(aS1 + k0, aD + 1024);
    gll16(bS0 + k0, bD);
    gll16(bS1 + k0, bD + 1024);
    __syncthreads();
    long af[4][2], bfr[4][2];
    #pragma unroll
    for (int fm=0; fm<4; fm++){
      const char* base = (const char*)As + (wm*64 + fm*16 + r)*64;
      af[fm][0] = *(const long*)(base + p0);
      af[fm][1] = *(const long*)(base + (p0 ^ 32));
    }
    #pragma unroll
    for (int fn=0; fn<4; fn++){
      const char* base = (const char*)Bs + (wn*64 + fn*16 + r)*64;
      bfr[fn][0] = *(const long*)(base + p0);
      bfr[fn][1] = *(const long*)(base + (p0 ^ 32));
    }
    #pragma unroll
    for (int fm=0; fm<4; fm++)
      #pragma unroll
      for (int fn=0; fn<4; fn++){
        acc[fm][fn] = __builtin_amdgcn_mfma_f32_16x16x32_fp8_fp8(af[fm][0], bfr[fn][0], acc[fm][fn], 0, 0, 0);
        acc[fm][fn] = __builtin_amdgcn_mfma_f32_16x16x32_fp8_fp8(af[fm][1], bfr[fn][1], acc[fm][fn], 0, 0, 0);
      }
  }
  const float inv32 = 1.f/32.f;
  #pragma unroll
  for (int fm=0; fm<4; fm++){
    #pragma unroll
    for (int fn=0; fn<4; fn++){
      int col = bcol + wn*64 + fn*16 + r;
      float bias = b2[col];
      #pragma unroll
      for (int q=0; q<4; q++){
        long row = brow + wm*64 + fm*16 + hi*4 + q;
        C8[row*512 + col] = f2e8(acc[fm][fn][q]*inv32 + bias);
      }
    }
  }
}

// ---- fused LSTM: gates (4 rows per wave, same d) + cell; fp8 weights -----
__global__ __launch_bounds__(256) void k_glstm(
    const float* __restrict__ x, const float* __restrict__ h_in,
    const float* __restrict__ c_in,
    const unsigned char* __restrict__ Wih, const unsigned char* __restrict__ Whh,
    const float* __restrict__ b_ih, const float* __restrict__ b_hh,
    float* __restrict__ h_out, float* __restrict__ c_out, int first)
{
  const int wid = threadIdx.x >> 6, lane = threadIdx.x & 63;
  const int d = (blockIdx.x >> 1)*4 + wid;
  const int n0 = (blockIdx.x & 1) << 4;
  float wi[4][16], wh[4][16], bias[4];
  #pragma unroll
  for (int g=0; g<4; g++){
    const int rg = g*1024 + d;
    const long wo = (long)rg*1024 + lane*16;
    uint4 vi = *(const uint4*)(Wih + wo);
    uint4 vh = *(const uint4*)(Whh + wo);
    DEC8X4(&wi[g][0],  vi.x); DEC8X4(&wi[g][4],  vi.y);
    DEC8X4(&wi[g][8],  vi.z); DEC8X4(&wi[g][12], vi.w);
    DEC8X4(&wh[g][0],  vh.x); DEC8X4(&wh[g][4],  vh.y);
    DEC8X4(&wh[g][8],  vh.z); DEC8X4(&wh[g][12], vh.w);
    bias[g] = b_ih[rg] + b_hh[rg];
  }
  const float inv32 = 1.f/32.f;
  for (int n=n0; n<n0+16; n++){
    const float4* hp = (const float4*)(h_in + n*1024 + lane*16);
    float ha[16];
    *(float4*)(ha+0)=hp[0]; *(float4*)(ha+4)=hp[1]; *(float4*)(ha+8)=hp[2]; *(float4*)(ha+12)=hp[3];
    float s0=0.f, s1=0.f, s2=0.f, s3=0.f;
    if (first){
      #pragma unroll
      for (int i=0;i<16;i++){
        s0 += ha[i]*wh[0][i]; s1 += ha[i]*wh[1][i];
        s2 += ha[i]*wh[2][i]; s3 += ha[i]*wh[3][i];
      }
    } else {
      const float4* xp = (const float4*)(x + n*1024 + lane*16);
      float xa[16];
      *(float4*)(xa+0)=xp[0]; *(float4*)(xa+4)=xp[1]; *(float4*)(xa+8)=xp[2]; *(float4*)(xa+12)=xp[3];
      #pragma unroll
      for (int i=0;i<16;i++){
        s0 += xa[i]*wi[0][i] + ha[i]*wh[0][i];
        s1 += xa[i]*wi[1][i] + ha[i]*wh[1][i];
        s2 += xa[i]*wi[2][i] + ha[i]*wh[2][i];
        s3 += xa[i]*wi[3][i] + ha[i]*wh[3][i];
      }
    }
    #pragma unroll
    for (int o=32;o>0;o>>=1){
      s0 += __shfl_xor(s0, o); s1 += __shfl_xor(s1, o);
      s2 += __shfl_xor(s2, o); s3 += __shfl_xor(s3, o);
    }
    if (lane == 0){
      const int idx = n*1024 + d;
      float gi = sigm(s0*inv32 + bias[0]);
      float gf = sigm(s1*inv32 + bias[1]);
      float gg = tanh_f(s2*inv32 + bias[2]);
      float go = sigm(s3*inv32 + bias[3]);
      float cn = gf*c_in[idx] + gi*gg;
      c_out[idx] = cn;
      h_out[idx] = go * tanh_f(cn);
    }
  }
}

// ---------------- q projection: wave-per-2j, n split over 2 blocks --------
__global__ __launch_bounds__(256) void k_q(
    const float* __restrict__ h, const unsigned short* __restrict__ W1,
    const float* __restrict__ b1, float* __restrict__ q)
{
  const int wid = threadIdx.x >> 6, lane = threadIdx.x & 63;
  const int jgrp = blockIdx.x >> 1;
  const int n0 = (blockIdx.x & 1) << 4;
  const int j0 = (jgrp*4 + wid)*2;
  float wf[2][16], bias[2];
  #pragma unroll
  for (int jj=0;jj<2;jj++){
    const long wo = (long)(j0+jj)*1024 + lane*16;
    short8 w0 = *(const short8*)(W1 + wo);
    short8 w1 = *(const short8*)(W1 + wo + 8);
    #pragma unroll
    for (int i=0;i<8;i++){ wf[jj][i] = b2f((unsigned short)w0[i]); wf[jj][i+8] = b2f((unsigned short)w1[i]); }
    bias[jj] = b1[j0+jj];
  }
  for (int n=n0; n<n0+16; n++){
    const float4* hp = (const float4*)(h + n*1024 + lane*16);
    float ha[16];
    *(float4*)(ha+0)=hp[0]; *(float4*)(ha+4)=hp[1]; *(float4*)(ha+8)=hp[2]; *(float4*)(ha+12)=hp[3];
    float s0=0.f, s1=0.f;
    #pragma unroll
    for (int i=0;i<16;i++){ s0 += ha[i]*wf[0][i]; s1 += ha[i]*wf[1][i]; }
    #pragma unroll
    for (int o=32;o>0;o>>=1){ s0 += __shfl_xor(s0, o); s1 += __shfl_xor(s1, o); }
    if (lane == 0){ q[n*AA + j0] = s0 + bias[0]; q[n*AA + j0 + 1] = s1 + bias[1]; }
  }
}

// ---- fused attn + softmax(no-max) + x_next partials (fp8, ILP-batched) ---
__global__ __launch_bounds__(256) void k_attnx(
    const unsigned char* __restrict__ ep8, const float* __restrict__ qv,
    const float* __restrict__ w3, const float* __restrict__ b3p,
    const int* __restrict__ mask, const unsigned char* __restrict__ enc8,
    float* __restrict__ out, float* __restrict__ part,
    float* __restrict__ psum, int t)
{
  const int n = blockIdx.y, ch = blockIdx.x;
  const int tid = threadIdx.x;
  const int wid = tid >> 6, lane = tid & 63;
  __shared__ float p_s[64];

  float qf[8], w3f[8];
  const float4* qp = (const float4*)(qv + n*AA + lane*8);
  *(float4*)(qf+0) = qp[0]; *(float4*)(qf+4) = qp[1];
  const float4* wp = (const float4*)(w3 + lane*8);
  *(float4*)(w3f+0) = wp[0]; *(float4*)(w3f+4) = wp[1];
  const float b3v = b3p[0];

  // phase 1: batch all 16 ep loads up front (16 outstanding -> latency hidden)
  uint2 e[16];
  {
    const unsigned char* epb = ep8 + ((long)n*LL + ch*64 + wid*16)*AA + lane*8;
    #pragma unroll
    for (int li=0; li<16; li++)
      e[li] = *(const uint2*)(epb + (long)li*AA);
  }
  #pragma unroll
  for (int li = 0; li < 16; li++){
    const int l = ch*64 + wid*16 + li;
    float ef[8];
    DEC8X4(&ef[0], e[li].x); DEC8X4(&ef[4], e[li].y);
    float s = 0.f;
    #pragma unroll
    for (int i=0;i<8;i++) s += tanh_f(ef[i] + qf[i]) * w3f[i];
    #pragma unroll
    for (int o=32;o>0;o>>=1) s += __shfl_xor(s, o);
    if (lane == 0){
      float a = s + b3v;
      int mk = mask[n*LL + l];
      float aout = a;
      if (!mk) aout += -1e30f;
      out[((long)n*TT + t)*LL + l] = aout;
      p_s[wid*16 + li] = mk ? EXP2(a*LOG2E) : 0.f;
    }
  }
  __syncthreads();

  // phase 2: groups of 16 (16 outstanding 4B loads per group)
  const unsigned char* base = enc8 + ((long)n*LL + ch*64)*1024 + tid*4;
  float a0=0.f, a1=0.f, a2=0.f, a3=0.f;
  #pragma unroll 1
  for (int lg=0; lg<64; lg+=16){
    unsigned u[16];
    #pragma unroll
    for (int i=0;i<16;i++) u[i] = *(const unsigned*)(base + (long)(lg+i)*1024);
    #pragma unroll
    for (int i=0;i<16;i++){
      float pv = p_s[lg+i];
      a0 = fmaf(pv, DEC8(u[i],0), a0);
      a1 = fmaf(pv, DEC8(u[i],1), a1);
      a2 = fmaf(pv, DEC8(u[i],2), a2);
      a3 = fmaf(pv, DEC8(u[i],3), a3);
    }
  }
  float4 o = {a0,a1,a2,a3};
  *(float4*)(part + ((long)(n*32+ch))*1024 + tid*4) = o;
  if (tid == 0){
    float S = 0.f;
    #pragma unroll
    for (int i=0;i<64;i++) S += p_s[i];
    psum[n*32 + ch] = S;
  }
}

// ---------------- reduce partials -> x (divide by total sum) --------------
__global__ __launch_bounds__(256) void k_xreduce(const float* __restrict__ part,
                                                 const float* __restrict__ psum,
                                                 float* __restrict__ x){
  int idx = blockIdx.x*256 + threadIdx.x;
  int n = idx >> 10, d = idx & 1023;
  float S = 0.f;
  #pragma unroll
  for (int ch=0; ch<32; ch++) S += psum[n*32 + ch];
  float s = 0.f;
  #pragma unroll
  for (int ch=0; ch<32; ch++) s += part[((long)(n*32+ch))*1024 + d];
  x[idx] = s * RCP(S);
}

extern "C" void kernel_launch(void* const* d_in, const int* in_sizes, int n_in,
                              void* d_out, int out_size, void* d_ws, size_t ws_size,
                              hipStream_t stream){
  const float* enc_f = (const float*)d_in[0];
  const float* h0    = (const float*)d_in[1];
  const float* c0    = (const float*)d_in[2];
  const int*   mask  = (const int*)d_in[3];
  const float* Wih_f = (const float*)d_in[4];
  const float* Whh_f = (const float*)d_in[5];
  const float* b_ih  = (const float*)d_in[6];
  const float* b_hh  = (const float*)d_in[7];
  const float* W1_f  = (const float*)d_in[8];
  const float* b1    = (const float*)d_in[9];
  const float* W2_f  = (const float*)d_in[10];
  const float* b2    = (const float*)d_in[11];
  const float* w3    = (const float*)d_in[12];
  const float* b3    = (const float*)d_in[13];
  float* out = (float*)d_out;

  char* ws = (char*)d_ws;
  size_t off = 0;
  auto alloc = [&](size_t bytes){ void* p = ws + off; off += (bytes + 255) & ~255ull; return p; };
  unsigned char*  enc_8 = (unsigned char*)alloc((size_t)NB*LL*DD);     // 64 MB fp8
  unsigned char*  ep_8  = (unsigned char*)alloc((size_t)NB*LL*AA);     // 32 MB fp8
  unsigned char*  Wih_8 = (unsigned char*)alloc((size_t)4*DD*DD);      // 4 MB fp8 x32
  unsigned char*  Whh_8 = (unsigned char*)alloc((size_t)4*DD*DD);      // 4 MB fp8 x32
  unsigned short* W1_b  = (unsigned short*)alloc((size_t)AA*DD*2);
  unsigned char*  W2_8  = (unsigned char*)alloc((size_t)AA*DD);        // fp8 x32
  float* hA    = (float*)alloc((size_t)NB*DD*4);
  float* hB    = (float*)alloc((size_t)NB*DD*4);
  float* cbuf  = (float*)alloc((size_t)NB*DD*4);
  float* xbuf  = (float*)alloc((size_t)NB*DD*4);
  float* qbuf  = (float*)alloc((size_t)NB*AA*4);
  float* part  = (float*)alloc((size_t)NB*32*DD*4);
  float* psum  = (float*)alloc((size_t)NB*32*4);

  k_cvt_all<<<4096,256,0,stream>>>(enc_f, Wih_f, Whh_f, W1_f, W2_f,
                                   enc_8, Wih_8, Whh_8, W1_b, W2_8,
                                   (long)NB*LL*DD/8, (long)4*DD*DD/8,
                                   (long)AA*DD/8, (long)AA*DD/8);
  k_gemm8<<<dim3(512,4),256,0,stream>>>(enc_8, W2_8, b2, ep_8);

  float* hcur = hA; float* hnxt = hB;
  for (int t=0; t<TT; t++){
    k_glstm<<<512,256,0,stream>>>(xbuf,
                                  t==0 ? h0 : hcur,
                                  t==0 ? c0 : cbuf,
                                  Wih_8, Whh_8, b_ih, b_hh,
                                  hnxt, cbuf, t==0 ? 1 : 0);
    k_q<<<128,256,0,stream>>>(hnxt, W1_b, b1, qbuf);
    k_attnx<<<dim3(32,NB),256,0,stream>>>(ep_8, qbuf, w3, b3, mask, enc_8,
                                          out, part, psum, t);
    k_xreduce<<<128,256,0,stream>>>(part, psum, xbuf);
    float* tmp = hcur; hcur = hnxt; hnxt = tmp;
  }
}